// Round 22
// baseline (1626.333 us; speedup 1.0000x reference)
//
#include <hip/hip_runtime.h>
#include <hip/hip_bf16.h>
#include <math.h>

#define BB_ 64
#define TT_ 256
#define DD_ 512
#define HH_ 512
#define G4_ 2048
#define ODE_ 256

#define NBLK_ 512   // persistent LSTM grid: 32 j-blocks x 16 b-groups, 2 blocks/CU

// Coherent (cross-XCD) loads/stores: RELAXED AGENT atomics -> sc1 global ops,
// bypass stale per-XCD L2, hit the Infinity Cache coherence point, and emit
// NO cache-wide maintenance (unlike acquire/release).
__device__ __forceinline__ float2 cohload2(const float* p) {
    unsigned long long u = __hip_atomic_load(
        (unsigned long long*)p, __ATOMIC_RELAXED, __HIP_MEMORY_SCOPE_AGENT);
    union { unsigned long long u; float2 f; } c; c.u = u;
    return c.f;
}
__device__ __forceinline__ void cohstore2(float* p, float a, float b) {
    union { unsigned long long u; float2 f; } c; c.f = make_float2(a, b);
    __hip_atomic_store((unsigned long long*)p, c.u,
                       __ATOMIC_RELAXED, __HIP_MEMORY_SCOPE_AGENT);
}

// Fast overflow-safe sigmoid / tanh built on v_exp_f32.
__device__ __forceinline__ float fsigmoid(float x) {
    return 1.f / (1.f + __expf(-x));
}
__device__ __forceinline__ float ftanh(float x) {
    float e = __expf(-2.f * fabsf(x));     // in (0,1], never overflows
    float t = (1.f - e) / (1.f + e);
    return copysignf(t, x);
}

// DPP row-rotate-add: s + rotate_right_within_row16(s, N). Pure VALU (no LDS
// pipe, unlike ds_bpermute-based __shfl_xor). CTRL: 0x120 + N = row_ror:N.
template <int CTRL>
__device__ __forceinline__ float dpp_ror_add(float x) {
    int y = __builtin_amdgcn_update_dpp(0, __float_as_int(x), CTRL, 0xf, 0xf, false);
    return x + __int_as_float(y);
}
// Allreduce over the 16-lane row: every lane ends with the row total.
__device__ __forceinline__ float row16_allreduce(float x) {
    x = dpp_ror_add<0x121>(x);   // + ror 1
    x = dpp_ror_add<0x122>(x);   // + ror 2
    x = dpp_ror_add<0x124>(x);   // + ror 4
    x = dpp_ror_add<0x128>(x);   // + ror 8
    return x;
}

// ---------------------------------------------------------------------------
// fp32 GEMM:  C[m,n] = act( scale * sum_k A[m,k]*W[n,k] + bias1[n] (+bias2[n]) )
// A: M x K row-major, W: N x K row-major (computes A @ W.T).
// 128x128 tile, BK=16, register prefetch + LDS DOUBLE BUFFER: one
// __syncthreads per K-tile (was two). At iter i: sync -> write regs(tile i+1)
// to buf[(i+1)&1] (iter i-1's reads of that buffer completed at the sync) ->
// fetch tile i+2 to regs -> compute tile i from buf[i&1]. FMA order identical.
// REQUIRES M % 128 == 0 (tail GEMMs are fused into fused_tail).
// (r20 change, retested on a clean machine — r20's bench ran on a machine
// under heavy external load and was inconclusive.)
// ---------------------------------------------------------------------------
template <int ACT>  // 0 = none, 1 = tanh
__global__ __launch_bounds__(256) void gemm_bt(
    const float* __restrict__ A, const float* __restrict__ W,
    const float* __restrict__ bias1, const float* __restrict__ bias2,
    float* __restrict__ C, int M, int N, int K, float scale)
{
    const int BM = 128, BN = 128, BK = 16;
    __shared__ float As[2][BK][BM + 4];
    __shared__ float Ws[2][BK][BN + 4];
    const int tid = threadIdx.x;
    const int tx = tid & 15, ty = tid >> 4;
    const int m0 = blockIdx.y * BM, n0 = blockIdx.x * BN;

    float acc[8][8];
#pragma unroll
    for (int i = 0; i < 8; ++i)
#pragma unroll
        for (int j = 0; j < 8; ++j) acc[i][j] = 0.f;

    const int r0_ = (tid * 4) >> 4,         c0_ = (tid * 4) & 15;
    const int r1_ = ((256 + tid) * 4) >> 4, c1_ = ((256 + tid) * 4) & 15;
    const int gm0 = m0 + r0_, gm1 = m0 + r1_;
    const int nt = K / BK;

    // fetch tile 0 -> regs, write to LDS buf0
    float4 pa0 = *(const float4*)(A + (size_t)gm0 * K + c0_);
    float4 pw0 = *(const float4*)(W + (size_t)(n0 + r0_) * K + c0_);
    float4 pa1 = *(const float4*)(A + (size_t)gm1 * K + c1_);
    float4 pw1 = *(const float4*)(W + (size_t)(n0 + r1_) * K + c1_);
    As[0][c0_ + 0][r0_] = pa0.x; As[0][c0_ + 1][r0_] = pa0.y;
    As[0][c0_ + 2][r0_] = pa0.z; As[0][c0_ + 3][r0_] = pa0.w;
    Ws[0][c0_ + 0][r0_] = pw0.x; Ws[0][c0_ + 1][r0_] = pw0.y;
    Ws[0][c0_ + 2][r0_] = pw0.z; Ws[0][c0_ + 3][r0_] = pw0.w;
    As[0][c1_ + 0][r1_] = pa1.x; As[0][c1_ + 1][r1_] = pa1.y;
    As[0][c1_ + 2][r1_] = pa1.z; As[0][c1_ + 3][r1_] = pa1.w;
    Ws[0][c1_ + 0][r1_] = pw1.x; Ws[0][c1_ + 1][r1_] = pw1.y;
    Ws[0][c1_ + 2][r1_] = pw1.z; Ws[0][c1_ + 3][r1_] = pw1.w;

    // fetch tile 1 -> regs
    if (nt > 1) {
        pa0 = *(const float4*)(A + (size_t)gm0 * K + BK + c0_);
        pw0 = *(const float4*)(W + (size_t)(n0 + r0_) * K + BK + c0_);
        pa1 = *(const float4*)(A + (size_t)gm1 * K + BK + c1_);
        pw1 = *(const float4*)(W + (size_t)(n0 + r1_) * K + BK + c1_);
    }

    for (int i = 0; i < nt; ++i) {
        __syncthreads();           // buf[i&1] readable; buf[(i+1)&1] free
        const int cur = i & 1;
        if (i + 1 < nt) {
            const int nb = cur ^ 1;
            As[nb][c0_ + 0][r0_] = pa0.x; As[nb][c0_ + 1][r0_] = pa0.y;
            As[nb][c0_ + 2][r0_] = pa0.z; As[nb][c0_ + 3][r0_] = pa0.w;
            Ws[nb][c0_ + 0][r0_] = pw0.x; Ws[nb][c0_ + 1][r0_] = pw0.y;
            Ws[nb][c0_ + 2][r0_] = pw0.z; Ws[nb][c0_ + 3][r0_] = pw0.w;
            As[nb][c1_ + 0][r1_] = pa1.x; As[nb][c1_ + 1][r1_] = pa1.y;
            As[nb][c1_ + 2][r1_] = pa1.z; As[nb][c1_ + 3][r1_] = pa1.w;
            Ws[nb][c1_ + 0][r1_] = pw1.x; Ws[nb][c1_ + 1][r1_] = pw1.y;
            Ws[nb][c1_ + 2][r1_] = pw1.z; Ws[nb][c1_ + 3][r1_] = pw1.w;
        }
        if (i + 2 < nt) {
            const int kn = (i + 2) * BK;
            pa0 = *(const float4*)(A + (size_t)gm0 * K + kn + c0_);
            pw0 = *(const float4*)(W + (size_t)(n0 + r0_) * K + kn + c0_);
            pa1 = *(const float4*)(A + (size_t)gm1 * K + kn + c1_);
            pw1 = *(const float4*)(W + (size_t)(n0 + r1_) * K + kn + c1_);
        }
#pragma unroll
        for (int k = 0; k < BK; ++k) {
            float a[8], w[8];
#pragma unroll
            for (int q = 0; q < 8; ++q) a[q] = As[cur][k][ty * 8 + q];
#pragma unroll
            for (int j = 0; j < 8; ++j) w[j] = Ws[cur][k][tx * 8 + j];
#pragma unroll
            for (int q = 0; q < 8; ++q)
#pragma unroll
                for (int j = 0; j < 8; ++j) acc[q][j] += a[q] * w[j];
        }
    }

#pragma unroll
    for (int j = 0; j < 8; ++j) {
        int n = n0 + tx * 8 + j;
        float bsum = bias1[n] + (bias2 ? bias2[n] : 0.f);
#pragma unroll
        for (int i = 0; i < 8; ++i) {
            int m = m0 + ty * 8 + i;
            float v = acc[i][j] * scale + bsum;
            if (ACT == 1) v = tanhf(v);
            C[(size_t)m * N + n] = v;
        }
    }
}

// ---------------------------------------------------------------------------
// Persistent LSTM recurrence (r18 verbatim — best measured: 915 us).
// 512 blocks x 256 threads = 2 blocks/CU from DIFFERENT barrier groups.
// Block: bg = blockIdx.x >> 5 (contiguous groups of 32), jb = blockIdx.x & 31.
// Whh slice in 128 REGISTERS; h double-buffer bg-blocked [16][512 jh][4 b];
// h_s [k][4b] stride 12; DPP row_ror allreduce; barrier = fetch_add arrivals
// + last-arriver release FLAG on a store-only L3-resident line.
// ---------------------------------------------------------------------------
__global__ __launch_bounds__(256, 2) void lstm_persist(
    const float* __restrict__ gx,     // (B, T, 4H) gate preacts from x (biases included)
    const float* __restrict__ Whh,    // (4H, H)
    const float* __restrict__ ac0,    // (B, H)
    float* __restrict__ hT0,          // blocked (16 bg)(512 jh)(4 b), holds h0 at entry
    float* __restrict__ hT1,          // same, buffer 1
    float* __restrict__ hsT,          // (T, H, B) transposed per-step h (for attention)
    unsigned* __restrict__ cnt)       // counters at [bg*32]; flags at [2048 + bg*32]
{
    __shared__ float h_s[512 * 12];       // [k][b] stride 12 (4 used)  (24.6 KB)
    __shared__ float gx_s[4 * 65];        // [b_local][g*16+jl], padded ( 1.0 KB)

    const int tid = threadIdx.x;
    const int bg = blockIdx.x >> 5;       // 0..15 (contiguous groups)
    const int jb = blockIdx.x & 31;       // 0..31
    const int jh0 = jb * 16;
    const int b0  = bg * 4;
    const int kq   = tid & 15;
    const int jh_l = tid >> 4;            // 0..15
    const int jh   = jh0 + jh_l;

    // ---- per-thread state: lanes kq<4 own one (b, jh) pair ----
    float creg = 0.f;
    if (kq < 4) creg = ac0[(size_t)(b0 + kq) * HH_ + jh];

    // ---- Whh slice into REGISTERS (loop-invariant; 128 VGPRs).
    //      wreg[kk] = {W_i,W_f,W_g,W_o}[jh][k=kk*16+kq]. ----
    float4 wreg[32];
#pragma unroll
    for (int kk = 0; kk < 32; ++kk) {
        int k = kk * 16 + kq;
        wreg[kk].x = Whh[(size_t)(0 * 512 + jh) * 512 + k];
        wreg[kk].y = Whh[(size_t)(1 * 512 + jh) * 512 + k];
        wreg[kk].z = Whh[(size_t)(2 * 512 + jh) * 512 + k];
        wreg[kk].w = Whh[(size_t)(3 * 512 + jh) * 512 + k];
    }

    // gx stage mapping: thread (lb, g, jl) loads ONE float
    const int g_lb = tid >> 6;             // 0..3 local batch
    const int g_g  = (tid >> 4) & 3;       // gate
    const int g_jl = tid & 15;             // jl
    const float* gsrc = gx + (size_t)(b0 + g_lb) * TT_ * G4_ + g_g * 512 + jh0 + g_jl;

    // prefetch gx for t = 0 (t_orig = 255)
    float gxreg = gsrc[(size_t)255 * G4_];

    for (int t = 0; t < TT_; ++t) {
        const float* hin = ((t & 1) ? hT1 : hT0) + (size_t)bg * 2048;
        float* hout      = ((t & 1) ? hT0 : hT1) + (size_t)bg * 2048;

        // publish this step's gx slice to LDS
        gx_s[g_lb * 65 + g_g * 16 + g_jl] = gxreg;

        // ---- stage h: 8 KB contiguous -> LDS (2 chunks of 4 floats/thread) ----
        float4 hstg[2];
#pragma unroll
        for (int w = 0; w < 2; ++w) {
            int c = w * 256 + tid;                   // chunk id, floats [c*4, c*4+4)
            float2 a  = cohload2(hin + (size_t)c * 4);
            float2 b2 = cohload2(hin + (size_t)c * 4 + 2);
            hstg[w] = make_float4(a.x, a.y, b2.x, b2.y);
        }
#pragma unroll
        for (int w = 0; w < 2; ++w) {
            int c = w * 256 + tid;                   // row c, full 4-float row
            *(float4*)(h_s + (size_t)c * 12) = hstg[w];
        }
        __syncthreads();     // h_s + gx_s ready

        // prefetch next step's gx (latency hides under compute)
        if (t + 1 < TT_)
            gxreg = gsrc[(size_t)(TT_ - 2 - t) * G4_];

        // ---- h @ Whh.T, thread's k = kk*16 + kq (32 k, 4 b, 4 gates) ----
        float acc[4][4];
#pragma unroll
        for (int i = 0; i < 4; ++i)
#pragma unroll
            for (int j = 0; j < 4; ++j) acc[i][j] = 0.f;

#pragma unroll
        for (int kk = 0; kk < 32; ++kk) {
            int k = kk * 16 + kq;
            float4 wv = wreg[kk];
            float4 ha = *(const float4*)(h_s + (size_t)k * 12);
            float hv[4] = {ha.x, ha.y, ha.z, ha.w};
#pragma unroll
            for (int bb = 0; bb < 4; ++bb) {
                acc[bb][0] += hv[bb] * wv.x;
                acc[bb][1] += hv[bb] * wv.y;
                acc[bb][2] += hv[bb] * wv.z;
                acc[bb][3] += hv[bb] * wv.w;
            }
        }

        // ---- DPP rotation allreduce over the 16-lane row (pure VALU) ----
#pragma unroll
        for (int bb = 0; bb < 4; ++bb)
#pragma unroll
            for (int g = 0; g < 4; ++g)
                acc[bb][g] = row16_allreduce(acc[bb][g]);

        // ---- gates + state update (lanes kq<4; lane kq owns batch b0+kq) ----
        float hn = 0.f;
        if (kq < 4) {
            float gi = 0.f, gf = 0.f, gg = 0.f, go = 0.f;
#pragma unroll
            for (int bb = 0; bb < 4; ++bb)
                if (kq == bb) { gi = acc[bb][0]; gf = acc[bb][1];
                                gg = acc[bb][2]; go = acc[bb][3]; }
            gi += gx_s[kq * 65 + 0 * 16 + jh_l];
            gf += gx_s[kq * 65 + 1 * 16 + jh_l];
            gg += gx_s[kq * 65 + 2 * 16 + jh_l];
            go += gx_s[kq * 65 + 3 * 16 + jh_l];
            float si = fsigmoid(gi);
            float sf = fsigmoid(gf);
            float sg = ftanh(gg);
            float so = fsigmoid(go);
            creg = sf * creg + si * sg;
            hn = so * ftanh(creg);
        }
        // pair (b, b+1) values: even kq lane also gets kq+1's hn
        float hn_up = __shfl_down(hn, 1);
        const bool do_st = (kq < 4) && ((kq & 1) == 0);
        if (do_st)
            cohstore2(hout + (size_t)jh * 4 + kq, hn, hn_up);

        // ---- per-group grid barrier: fetch_add arrivals + release FLAG ----
        __syncthreads();   // drains vmcnt per wave: h stores acked at L3 before flag
        if (tid == 0) {
            unsigned old = __hip_atomic_fetch_add(&cnt[(size_t)bg * 32], 1u,
                                   __ATOMIC_RELAXED, __HIP_MEMORY_SCOPE_AGENT);
            if (old == (unsigned)(t + 1) * 32u - 1u)   // last arriver releases
                __hip_atomic_store(&cnt[2048 + (size_t)bg * 32], (unsigned)(t + 1),
                                   __ATOMIC_RELAXED, __HIP_MEMORY_SCOPE_AGENT);
        }
        if (do_st)         // history store: drain overlaps the poll
            *(float2*)(hsT + ((size_t)t * 512 + jh) * 64 + b0 + kq) = make_float2(hn, hn_up);
        if (tid == 0) {
            while (__hip_atomic_load(&cnt[2048 + (size_t)bg * 32],
                        __ATOMIC_RELAXED, __HIP_MEMORY_SCOPE_AGENT) < (unsigned)(t + 1))
                __builtin_amdgcn_s_sleep(1);
        }
        __syncthreads();
    }
}

// h0 -> blocked layout [bg][jh][4b]
__global__ __launch_bounds__(256) void h0_transpose(
    const float* __restrict__ ah0, float* __restrict__ hT0)
{
    int idx = blockIdx.x * 256 + threadIdx.x;   // 32768
    int b = idx >> 9, jh = idx & 511;
    hT0[(size_t)(b >> 2) * 2048 + jh * 4 + (b & 3)] = ah0[idx];
}

// score[b][t_orig] = dot(hsT[ts][:][b], Wa) + ba,  ts = T-1-t_orig
__global__ __launch_bounds__(256) void att_scores_T(
    const float* __restrict__ hsT, const float* __restrict__ Wa,
    const float* __restrict__ ba, float* __restrict__ scores)
{
    int ts = blockIdx.x;
    int b = threadIdx.x & 63, part = threadIdx.x >> 6;
    const float* hp = hsT + (size_t)ts * 512 * 64;
    float s = 0.f;
#pragma unroll 8
    for (int jj = 0; jj < 128; ++jj) {
        int jh = part * 128 + jj;
        s += hp[(size_t)jh * 64 + b] * Wa[jh];
    }
    __shared__ float red[4][64];
    red[part][b] = s;
    __syncthreads();
    if (part == 0) {
        float tot = red[0][b] + red[1][b] + red[2][b] + red[3][b] + ba[0];
        scores[b * TT_ + (TT_ - 1 - ts)] = tot;
    }
}

// ---------------------------------------------------------------------------
// Fused tail: per-batch block does softmax(alpha) + weighted emb sum (svec),
// beta = tanh(hT @ W_batt.T + b), var = beta*svec, mu = (var/256)@W_mu.T + b,
// sigma = var@W_sig.T + b.
// ---------------------------------------------------------------------------
__global__ __launch_bounds__(256) void fused_tail(
    const float* __restrict__ scores,  // (B, T)
    const float* __restrict__ emb,     // (B, T, D)
    const float* __restrict__ hTT,     // blocked (16)(512)(4)
    const float* __restrict__ W_batt, const float* __restrict__ b_batt,
    const float* __restrict__ W_mu,   const float* __restrict__ b_mu,
    const float* __restrict__ W_sig,  const float* __restrict__ b_sig,
    float* __restrict__ out_mu, float* __restrict__ out_sig)
{
    const int b = blockIdx.x;
    const int tid = threadIdx.x;
    const int wv = tid >> 6, ln = tid & 63;
    __shared__ float sm[256];     // alpha
    __shared__ float sv_s[512];   // svec, then var
    __shared__ float hT_s[512];   // hT for this batch
    __shared__ float red[16];

    // ---- softmax over T ----
    float v = scores[b * TT_ + tid];
    float m = v;
#pragma unroll
    for (int off = 32; off; off >>= 1) m = fmaxf(m, __shfl_xor(m, off));
    if (ln == 0) red[wv] = m;
    // hT load overlaps reduction
    hT_s[tid]       = hTT[(size_t)(b >> 2) * 2048 + (size_t)tid * 4 + (b & 3)];
    hT_s[tid + 256] = hTT[(size_t)(b >> 2) * 2048 + (size_t)(tid + 256) * 4 + (b & 3)];
    __syncthreads();
    float bm = fmaxf(fmaxf(red[0], red[1]), fmaxf(red[2], red[3]));
    float e = expf(v - bm);
    float ss = e;
#pragma unroll
    for (int off = 32; off; off >>= 1) ss += __shfl_xor(ss, off);
    if (ln == 0) red[8 + wv] = ss;
    __syncthreads();
    float tot = red[8] + red[9] + red[10] + red[11];
    sm[tid] = e / tot;
    __syncthreads();

    // ---- svec[d] = sum_t alpha[t] * emb[b,t,d] ----
    float acc0 = 0.f, acc1 = 0.f;
    const float* ep = emb + (size_t)b * TT_ * DD_;
    for (int t = 0; t < TT_; ++t) {
        float a = sm[t];
        acc0 += a * ep[t * DD_ + tid];
        acc1 += a * ep[t * DD_ + 256 + tid];
    }
    sv_s[tid] = acc0;
    sv_s[tid + 256] = acc1;
    __syncthreads();

    // ---- var[d] = tanh(hT . W_batt[d] + b_batt[d]) * svec[d], wave-dots ----
    for (int i = 0; i < 128; ++i) {
        int d = wv * 128 + i;
        const float* wr = W_batt + (size_t)d * 512;
        float s = 0.f;
#pragma unroll
        for (int q = 0; q < 8; ++q) s += wr[ln + q * 64] * hT_s[ln + q * 64];
#pragma unroll
        for (int off = 32; off; off >>= 1) s += __shfl_xor(s, off);
        if (ln == 0) sv_s[d] = ftanh(s + b_batt[d]) * sv_s[d];
    }
    __syncthreads();

    // ---- mu (o<256) / sigma (o>=256): wave-dots over var ----
    for (int i = 0; i < 128; ++i) {
        int o = wv * 128 + i;
        const float* wr = (o < 256) ? (W_mu + (size_t)o * 512)
                                    : (W_sig + (size_t)(o - 256) * 512);
        float s = 0.f;
#pragma unroll
        for (int q = 0; q < 8; ++q) s += wr[ln + q * 64] * sv_s[ln + q * 64];
#pragma unroll
        for (int off = 32; off; off >>= 1) s += __shfl_xor(s, off);
        if (ln == 0) {
            if (o < 256) out_mu[(size_t)b * ODE_ + o] = s * (1.f / 256.f) + b_mu[o];
            else         out_sig[(size_t)b * ODE_ + (o - 256)] = s + b_sig[o - 256];
        }
    }
}

extern "C" void kernel_launch(void* const* d_in, const int* in_sizes, int n_in,
                              void* d_out, int out_size, void* d_ws, size_t ws_size,
                              hipStream_t stream) {
    const float* x      = (const float*)d_in[0];
    const float* W_emb  = (const float*)d_in[1];
    const float* b_emb  = (const float*)d_in[2];
    const float* Wih_a  = (const float*)d_in[3];
    const float* Whh_a  = (const float*)d_in[4];
    const float* bih_a  = (const float*)d_in[5];
    const float* bhh_a  = (const float*)d_in[6];
    // d_in[7..10]: beta LSTM params — dead code in the reference, skipped.
    const float* W_aatt = (const float*)d_in[11];
    const float* b_aatt = (const float*)d_in[12];
    const float* W_batt = (const float*)d_in[13];
    const float* b_batt = (const float*)d_in[14];
    const float* W_mu   = (const float*)d_in[15];
    const float* b_mu   = (const float*)d_in[16];
    const float* W_sig  = (const float*)d_in[17];
    const float* b_sig  = (const float*)d_in[18];
    const float* ah0    = (const float*)d_in[19];
    const float* ac0    = (const float*)d_in[20];

    const size_t N_EMB = (size_t)BB_ * TT_ * DD_;   // 8,388,608
    const size_t N_GX  = (size_t)BB_ * TT_ * G4_;   // 33,554,432
    const size_t N_HS  = (size_t)TT_ * HH_ * BB_;   // 8,388,608
    const size_t N_BH  = (size_t)BB_ * HH_;         // 32,768
    const size_t N_BAR = 8192;                      // 32 KB barrier region

    size_t need_floats = N_BAR + N_EMB + N_GX + N_HS + 2 * N_BH
                       + (size_t)BB_ * TT_ + 3 * N_BH;
    if (ws_size < need_floats * sizeof(float)) return;

    float* ws     = (float*)d_ws;
    unsigned* cnt = (unsigned*)d_ws;                // counters + flags (32 KB)
    float* emb    = ws + N_BAR;
    float* gx     = emb + N_EMB;
    float* hsT    = gx + N_GX;
    float* hT0    = hsT + N_HS;
    float* hT1    = hT0 + N_BH;
    float* scores = hT1 + N_BH;

    float* out_mu  = (float*)d_out;
    float* out_sig = out_mu + (size_t)BB_ * ODE_;

    // 0. zero the barrier counters + flags (graph-capturable)
    hipMemsetAsync(d_ws, 0, N_BAR * sizeof(float), stream);

    // 1. h0 -> blocked layout
    h0_transpose<<<dim3(128), dim3(256), 0, stream>>>(ah0, hT0);

    // 2. emb = x @ W_emb.T + b_emb        (M=16384, N=512, K=512)
    gemm_bt<0><<<dim3(DD_ / 128, (BB_ * TT_) / 128), dim3(256), 0, stream>>>(
        x, W_emb, b_emb, nullptr, emb, BB_ * TT_, DD_, DD_, 1.f);

    // 3. gx = emb @ Wih_a.T + bih_a + bhh_a   (M=16384, N=2048, K=512)
    gemm_bt<0><<<dim3(G4_ / 128, (BB_ * TT_) / 128), dim3(256), 0, stream>>>(
        emb, Wih_a, bih_a, bhh_a, gx, BB_ * TT_, G4_, DD_, 1.f);

    // 4. full recurrence in ONE persistent kernel (512 blocks, 2/CU,
    //    per-group barrier with last-arriver release flag)
    lstm_persist<<<dim3(NBLK_), dim3(256), 0, stream>>>(
        gx, Whh_a, ac0, hT0, hT1, hsT, cnt);
    // final h lands in hT0 (t=255 writes buffer 0)

    // 5. attention scores
    att_scores_T<<<dim3(TT_), dim3(256), 0, stream>>>(hsT, W_aatt, b_aatt, scores);

    // 6. fused tail: softmax + wsum + beta + var + mu + sigma
    fused_tail<<<dim3(BB_), dim3(256), 0, stream>>>(
        scores, emb, hT0, W_batt, b_batt, W_mu, b_mu, W_sig, b_sig,
        out_mu, out_sig);
}

// Round 23
// 1565.445 us; speedup vs baseline: 1.0389x; 1.0389x over previous
//
#include <hip/hip_runtime.h>
#include <hip/hip_bf16.h>
#include <math.h>

#define BB_ 64
#define TT_ 256
#define DD_ 512
#define HH_ 512
#define G4_ 2048
#define ODE_ 256

#define NBLK_ 512   // persistent LSTM grid: 32 j-blocks x 16 b-groups, 2 blocks/CU

// Coherent (cross-XCD) loads/stores: RELAXED AGENT atomics -> sc1 global ops,
// bypass stale per-XCD L2, hit the Infinity Cache coherence point, and emit
// NO cache-wide maintenance (unlike acquire/release).
__device__ __forceinline__ float2 cohload2(const float* p) {
    unsigned long long u = __hip_atomic_load(
        (unsigned long long*)p, __ATOMIC_RELAXED, __HIP_MEMORY_SCOPE_AGENT);
    union { unsigned long long u; float2 f; } c; c.u = u;
    return c.f;
}
__device__ __forceinline__ void cohstore2(float* p, float a, float b) {
    union { unsigned long long u; float2 f; } c; c.f = make_float2(a, b);
    __hip_atomic_store((unsigned long long*)p, c.u,
                       __ATOMIC_RELAXED, __HIP_MEMORY_SCOPE_AGENT);
}

// Fast overflow-safe sigmoid / tanh built on v_exp_f32.
__device__ __forceinline__ float fsigmoid(float x) {
    return 1.f / (1.f + __expf(-x));
}
__device__ __forceinline__ float ftanh(float x) {
    float e = __expf(-2.f * fabsf(x));     // in (0,1], never overflows
    float t = (1.f - e) / (1.f + e);
    return copysignf(t, x);
}

// DPP row-rotate-add: s + rotate_right_within_row16(s, N). Pure VALU (no LDS
// pipe, unlike ds_bpermute-based __shfl_xor). CTRL: 0x120 + N = row_ror:N.
template <int CTRL>
__device__ __forceinline__ float dpp_ror_add(float x) {
    int y = __builtin_amdgcn_update_dpp(0, __float_as_int(x), CTRL, 0xf, 0xf, false);
    return x + __int_as_float(y);
}
// Allreduce over the 16-lane row: every lane ends with the row total.
__device__ __forceinline__ float row16_allreduce(float x) {
    x = dpp_ror_add<0x121>(x);   // + ror 1
    x = dpp_ror_add<0x122>(x);   // + ror 2
    x = dpp_ror_add<0x124>(x);   // + ror 4
    x = dpp_ror_add<0x128>(x);   // + ror 8
    return x;
}

// ---------------------------------------------------------------------------
// Generic fp32 GEMM:  C[m,n] = act( scale * sum_k A[m,k]*W[n,k] + bias1[n] (+bias2[n]) )
// A: M x K row-major, W: N x K row-major (computes A @ W.T).
// 128x128 tile, BK=16, register double-buffered (r15/r18-proven; LDS-dbuf,
// BK=32 and 256x128 all measured slower).
// ---------------------------------------------------------------------------
template <int ACT>  // 0 = none, 1 = tanh
__global__ __launch_bounds__(256) void gemm_bt(
    const float* __restrict__ A, const float* __restrict__ W,
    const float* __restrict__ bias1, const float* __restrict__ bias2,
    float* __restrict__ C, int M, int N, int K, float scale)
{
    const int BM = 128, BN = 128, BK = 16;
    __shared__ float As[BK][BM + 4];
    __shared__ float Ws[BK][BN + 4];
    const int tid = threadIdx.x;
    const int tx = tid & 15, ty = tid >> 4;
    const int m0 = blockIdx.y * BM, n0 = blockIdx.x * BN;

    float acc[8][8];
#pragma unroll
    for (int i = 0; i < 8; ++i)
#pragma unroll
        for (int j = 0; j < 8; ++j) acc[i][j] = 0.f;

    int r0_ = (tid * 4) >> 4,        c0_ = (tid * 4) & 15;
    int r1_ = ((256 + tid) * 4) >> 4, c1_ = ((256 + tid) * 4) & 15;
    int gm0 = m0 + r0_; if (gm0 > M - 1) gm0 = M - 1;
    int gm1 = m0 + r1_; if (gm1 > M - 1) gm1 = M - 1;

    float4 pa0 = *(const float4*)(A + (size_t)gm0 * K + c0_);
    float4 pw0 = *(const float4*)(W + (size_t)(n0 + r0_) * K + c0_);
    float4 pa1 = *(const float4*)(A + (size_t)gm1 * K + c1_);
    float4 pw1 = *(const float4*)(W + (size_t)(n0 + r1_) * K + c1_);

    for (int k0 = 0; k0 < K; k0 += BK) {
        As[c0_ + 0][r0_] = pa0.x; As[c0_ + 1][r0_] = pa0.y;
        As[c0_ + 2][r0_] = pa0.z; As[c0_ + 3][r0_] = pa0.w;
        Ws[c0_ + 0][r0_] = pw0.x; Ws[c0_ + 1][r0_] = pw0.y;
        Ws[c0_ + 2][r0_] = pw0.z; Ws[c0_ + 3][r0_] = pw0.w;
        As[c1_ + 0][r1_] = pa1.x; As[c1_ + 1][r1_] = pa1.y;
        As[c1_ + 2][r1_] = pa1.z; As[c1_ + 3][r1_] = pa1.w;
        Ws[c1_ + 0][r1_] = pw1.x; Ws[c1_ + 1][r1_] = pw1.y;
        Ws[c1_ + 2][r1_] = pw1.z; Ws[c1_ + 3][r1_] = pw1.w;
        __syncthreads();

        if (k0 + BK < K) {
            int kn = k0 + BK;
            pa0 = *(const float4*)(A + (size_t)gm0 * K + kn + c0_);
            pw0 = *(const float4*)(W + (size_t)(n0 + r0_) * K + kn + c0_);
            pa1 = *(const float4*)(A + (size_t)gm1 * K + kn + c1_);
            pw1 = *(const float4*)(W + (size_t)(n0 + r1_) * K + kn + c1_);
        }

#pragma unroll
        for (int k = 0; k < BK; ++k) {
            float a[8], w[8];
#pragma unroll
            for (int i = 0; i < 8; ++i) a[i] = As[k][ty * 8 + i];
#pragma unroll
            for (int j = 0; j < 8; ++j) w[j] = Ws[k][tx * 8 + j];
#pragma unroll
            for (int i = 0; i < 8; ++i)
#pragma unroll
                for (int j = 0; j < 8; ++j) acc[i][j] += a[i] * w[j];
        }
        __syncthreads();
    }

#pragma unroll
    for (int j = 0; j < 8; ++j) {
        int n = n0 + tx * 8 + j;
        float bsum = bias1[n] + (bias2 ? bias2[n] : 0.f);
#pragma unroll
        for (int i = 0; i < 8; ++i) {
            int m = m0 + ty * 8 + i;
            if (m < M) {
                float v = acc[i][j] * scale + bsum;
                if (ACT == 1) v = tanhf(v);
                C[(size_t)m * N + n] = v;
            }
        }
    }
}

// ---------------------------------------------------------------------------
// Persistent LSTM recurrence (r18 structure) + FUSED attention-score partials.
// 512 blocks x 256 threads = 2 blocks/CU from DIFFERENT barrier groups.
// Block: bg = blockIdx.x >> 5 (contiguous groups of 32), jb = blockIdx.x & 31.
// Whh slice in 128 REGISTERS; h double-buffer bg-blocked [16][512 jh][4 b];
// h_s [k][4b] stride 12; DPP row_ror allreduce; barrier = fetch_add arrivals
// + last-arriver release FLAG on a store-only L3-resident line.
// NEW: instead of storing the full h history (hsT, 32 MB), each step computes
// the rank-1 score partial  p = hn * Wa[jh]  (Wa loop-invariant, 1 VGPR),
// reduces over the block's 16 jh via tiny LDS, and stores ONE float per
// (batch, step) to ps[b][t_orig][jb]. att_scores_T kernel is eliminated;
// fused_tail sums the 32 jb-partials. b_aatt dropped (softmax shift-invariant).
// sc_s WAR safety: written before sync-A of step t, read by wave 0 before its
// poll; waves 1-3 wait at sync-B, so step t+1 writes can't precede the read.
// ---------------------------------------------------------------------------
__global__ __launch_bounds__(256, 2) void lstm_persist(
    const float* __restrict__ gx,     // (B, T, 4H) gate preacts from x (biases included)
    const float* __restrict__ Whh,    // (4H, H)
    const float* __restrict__ ac0,    // (B, H)
    const float* __restrict__ Wa,     // (H) attention vector
    float* __restrict__ hT0,          // blocked (16 bg)(512 jh)(4 b), holds h0 at entry
    float* __restrict__ hT1,          // same, buffer 1
    float* __restrict__ ps,           // (B, T, 32) score partials per j-block
    unsigned* __restrict__ cnt)       // counters at [bg*32]; flags at [2048 + bg*32]
{
    __shared__ float h_s[512 * 12];       // [k][b] stride 12 (4 used)  (24.6 KB)
    __shared__ float gx_s[4 * 65];        // [b_local][g*16+jl], padded ( 1.0 KB)
    __shared__ float sc_s[16 * 5];        // [jh_l][kq] score partials  ( 320 B)

    const int tid = threadIdx.x;
    const int bg = blockIdx.x >> 5;       // 0..15 (contiguous groups)
    const int jb = blockIdx.x & 31;       // 0..31
    const int jh0 = jb * 16;
    const int b0  = bg * 4;
    const int kq   = tid & 15;
    const int jh_l = tid >> 4;            // 0..15
    const int jh   = jh0 + jh_l;

    // ---- per-thread state: lanes kq<4 own one (b, jh) pair ----
    float creg = 0.f;
    if (kq < 4) creg = ac0[(size_t)(b0 + kq) * HH_ + jh];

    // ---- Whh slice into REGISTERS (loop-invariant; 128 VGPRs).
    //      wreg[kk] = {W_i,W_f,W_g,W_o}[jh][k=kk*16+kq]. ----
    float4 wreg[32];
#pragma unroll
    for (int kk = 0; kk < 32; ++kk) {
        int k = kk * 16 + kq;
        wreg[kk].x = Whh[(size_t)(0 * 512 + jh) * 512 + k];
        wreg[kk].y = Whh[(size_t)(1 * 512 + jh) * 512 + k];
        wreg[kk].z = Whh[(size_t)(2 * 512 + jh) * 512 + k];
        wreg[kk].w = Whh[(size_t)(3 * 512 + jh) * 512 + k];
    }
    const float wa = Wa[jh];               // loop-invariant attention weight

    // gx stage mapping: thread (lb, g, jl) loads ONE float
    const int g_lb = tid >> 6;             // 0..3 local batch
    const int g_g  = (tid >> 4) & 3;       // gate
    const int g_jl = tid & 15;             // jl
    const float* gsrc = gx + (size_t)(b0 + g_lb) * TT_ * G4_ + g_g * 512 + jh0 + g_jl;

    // prefetch gx for t = 0 (t_orig = 255)
    float gxreg = gsrc[(size_t)255 * G4_];

    for (int t = 0; t < TT_; ++t) {
        const float* hin = ((t & 1) ? hT1 : hT0) + (size_t)bg * 2048;
        float* hout      = ((t & 1) ? hT0 : hT1) + (size_t)bg * 2048;

        // publish this step's gx slice to LDS
        gx_s[g_lb * 65 + g_g * 16 + g_jl] = gxreg;

        // ---- stage h: 8 KB contiguous -> LDS (2 chunks of 4 floats/thread) ----
        float4 hstg[2];
#pragma unroll
        for (int w = 0; w < 2; ++w) {
            int c = w * 256 + tid;                   // chunk id, floats [c*4, c*4+4)
            float2 a  = cohload2(hin + (size_t)c * 4);
            float2 b2 = cohload2(hin + (size_t)c * 4 + 2);
            hstg[w] = make_float4(a.x, a.y, b2.x, b2.y);
        }
#pragma unroll
        for (int w = 0; w < 2; ++w) {
            int c = w * 256 + tid;                   // row c, full 4-float row
            *(float4*)(h_s + (size_t)c * 12) = hstg[w];
        }
        __syncthreads();     // h_s + gx_s ready

        // prefetch next step's gx (latency hides under compute)
        if (t + 1 < TT_)
            gxreg = gsrc[(size_t)(TT_ - 2 - t) * G4_];

        // ---- h @ Whh.T, thread's k = kk*16 + kq (32 k, 4 b, 4 gates) ----
        float acc[4][4];
#pragma unroll
        for (int i = 0; i < 4; ++i)
#pragma unroll
            for (int j = 0; j < 4; ++j) acc[i][j] = 0.f;

#pragma unroll
        for (int kk = 0; kk < 32; ++kk) {
            int k = kk * 16 + kq;
            float4 wv = wreg[kk];
            float4 ha = *(const float4*)(h_s + (size_t)k * 12);
            float hv[4] = {ha.x, ha.y, ha.z, ha.w};
#pragma unroll
            for (int bb = 0; bb < 4; ++bb) {
                acc[bb][0] += hv[bb] * wv.x;
                acc[bb][1] += hv[bb] * wv.y;
                acc[bb][2] += hv[bb] * wv.z;
                acc[bb][3] += hv[bb] * wv.w;
            }
        }

        // ---- DPP rotation allreduce over the 16-lane row (pure VALU) ----
#pragma unroll
        for (int bb = 0; bb < 4; ++bb)
#pragma unroll
            for (int g = 0; g < 4; ++g)
                acc[bb][g] = row16_allreduce(acc[bb][g]);

        // ---- gates + state update (lanes kq<4; lane kq owns batch b0+kq) ----
        float hn = 0.f;
        if (kq < 4) {
            float gi = 0.f, gf = 0.f, gg = 0.f, go = 0.f;
#pragma unroll
            for (int bb = 0; bb < 4; ++bb)
                if (kq == bb) { gi = acc[bb][0]; gf = acc[bb][1];
                                gg = acc[bb][2]; go = acc[bb][3]; }
            gi += gx_s[kq * 65 + 0 * 16 + jh_l];
            gf += gx_s[kq * 65 + 1 * 16 + jh_l];
            gg += gx_s[kq * 65 + 2 * 16 + jh_l];
            go += gx_s[kq * 65 + 3 * 16 + jh_l];
            float si = fsigmoid(gi);
            float sf = fsigmoid(gf);
            float sg = ftanh(gg);
            float so = fsigmoid(go);
            creg = sf * creg + si * sg;
            hn = so * ftanh(creg);
            sc_s[jh_l * 5 + kq] = hn * wa;     // score partial for this jh
        }
        // pair (b, b+1) values: even kq lane also gets kq+1's hn
        float hn_up = __shfl_down(hn, 1);
        const bool do_st = (kq < 4) && ((kq & 1) == 0);
        if (do_st)
            cohstore2(hout + (size_t)jh * 4 + kq, hn, hn_up);

        // ---- per-group grid barrier: fetch_add arrivals + release FLAG ----
        __syncthreads();   // drains vmcnt per wave: h stores acked at L3 before flag
        if (tid == 0) {
            unsigned old = __hip_atomic_fetch_add(&cnt[(size_t)bg * 32], 1u,
                                   __ATOMIC_RELAXED, __HIP_MEMORY_SCOPE_AGENT);
            if (old == (unsigned)(t + 1) * 32u - 1u)   // last arriver releases
                __hip_atomic_store(&cnt[2048 + (size_t)bg * 32], (unsigned)(t + 1),
                                   __ATOMIC_RELAXED, __HIP_MEMORY_SCOPE_AGENT);
        }
        if (tid < 4) {     // score-partial reduce+store: overlaps the poll
            float s = 0.f;
#pragma unroll
            for (int q = 0; q < 16; ++q) s += sc_s[q * 5 + tid];
            ps[((size_t)(b0 + tid) * TT_ + (TT_ - 1 - t)) * 32 + jb] = s;
        }
        if (tid == 0) {
            while (__hip_atomic_load(&cnt[2048 + (size_t)bg * 32],
                        __ATOMIC_RELAXED, __HIP_MEMORY_SCOPE_AGENT) < (unsigned)(t + 1))
                __builtin_amdgcn_s_sleep(1);
        }
        __syncthreads();
    }
}

// h0 -> blocked layout [bg][jh][4b]
__global__ __launch_bounds__(256) void h0_transpose(
    const float* __restrict__ ah0, float* __restrict__ hT0)
{
    int idx = blockIdx.x * 256 + threadIdx.x;   // 32768
    int b = idx >> 9, jh = idx & 511;
    hT0[(size_t)(b >> 2) * 2048 + jh * 4 + (b & 3)] = ah0[idx];
}

// ---------------------------------------------------------------------------
// Fused tail: per-batch block sums score partials -> softmax(alpha) ->
// weighted emb sum (svec) -> beta = tanh(hT @ W_batt.T + b) -> var=beta*svec
// -> mu = (var/256)@W_mu.T + b ; sigma = var@W_sig.T + b.
// (b_aatt omitted: softmax is invariant to a scalar shift.)
// ---------------------------------------------------------------------------
__global__ __launch_bounds__(256) void fused_tail(
    const float* __restrict__ ps,      // (B, T, 32) score partials
    const float* __restrict__ emb,     // (B, T, D)
    const float* __restrict__ hTT,     // blocked (16)(512)(4)
    const float* __restrict__ W_batt, const float* __restrict__ b_batt,
    const float* __restrict__ W_mu,   const float* __restrict__ b_mu,
    const float* __restrict__ W_sig,  const float* __restrict__ b_sig,
    float* __restrict__ out_mu, float* __restrict__ out_sig)
{
    const int b = blockIdx.x;
    const int tid = threadIdx.x;
    const int wv = tid >> 6, ln = tid & 63;
    __shared__ float sm[256];     // alpha
    __shared__ float sv_s[512];   // svec, then var
    __shared__ float hT_s[512];   // hT for this batch
    __shared__ float red[16];

    // ---- score[t] = sum of 32 jb-partials (deterministic ascending order) ----
    float v = 0.f;
    {
        const float* pp = ps + ((size_t)b * TT_ + tid) * 32;
#pragma unroll
        for (int q = 0; q < 32; ++q) v += pp[q];
    }

    // ---- softmax over T ----
    float m = v;
#pragma unroll
    for (int off = 32; off; off >>= 1) m = fmaxf(m, __shfl_xor(m, off));
    if (ln == 0) red[wv] = m;
    // hT load overlaps reduction
    hT_s[tid]       = hTT[(size_t)(b >> 2) * 2048 + (size_t)tid * 4 + (b & 3)];
    hT_s[tid + 256] = hTT[(size_t)(b >> 2) * 2048 + (size_t)(tid + 256) * 4 + (b & 3)];
    __syncthreads();
    float bm = fmaxf(fmaxf(red[0], red[1]), fmaxf(red[2], red[3]));
    float e = expf(v - bm);
    float ss = e;
#pragma unroll
    for (int off = 32; off; off >>= 1) ss += __shfl_xor(ss, off);
    if (ln == 0) red[8 + wv] = ss;
    __syncthreads();
    float tot = red[8] + red[9] + red[10] + red[11];
    sm[tid] = e / tot;
    __syncthreads();

    // ---- svec[d] = sum_t alpha[t] * emb[b,t,d] ----
    float acc0 = 0.f, acc1 = 0.f;
    const float* ep = emb + (size_t)b * TT_ * DD_;
    for (int t = 0; t < TT_; ++t) {
        float a = sm[t];
        acc0 += a * ep[t * DD_ + tid];
        acc1 += a * ep[t * DD_ + 256 + tid];
    }
    sv_s[tid] = acc0;
    sv_s[tid + 256] = acc1;
    __syncthreads();

    // ---- var[d] = tanh(hT . W_batt[d] + b_batt[d]) * svec[d], wave-dots ----
    for (int i = 0; i < 128; ++i) {
        int d = wv * 128 + i;
        const float* wr = W_batt + (size_t)d * 512;
        float s = 0.f;
#pragma unroll
        for (int q = 0; q < 8; ++q) s += wr[ln + q * 64] * hT_s[ln + q * 64];
#pragma unroll
        for (int off = 32; off; off >>= 1) s += __shfl_xor(s, off);
        if (ln == 0) sv_s[d] = ftanh(s + b_batt[d]) * sv_s[d];
    }
    __syncthreads();

    // ---- mu (o<256) / sigma (o>=256): wave-dots over var ----
    for (int i = 0; i < 128; ++i) {
        int o = wv * 128 + i;
        const float* wr = (o < 256) ? (W_mu + (size_t)o * 512)
                                    : (W_sig + (size_t)(o - 256) * 512);
        float s = 0.f;
#pragma unroll
        for (int q = 0; q < 8; ++q) s += wr[ln + q * 64] * sv_s[ln + q * 64];
#pragma unroll
        for (int off = 32; off; off >>= 1) s += __shfl_xor(s, off);
        if (ln == 0) {
            if (o < 256) out_mu[(size_t)b * ODE_ + o] = s * (1.f / 256.f) + b_mu[o];
            else         out_sig[(size_t)b * ODE_ + (o - 256)] = s + b_sig[o - 256];
        }
    }
}

extern "C" void kernel_launch(void* const* d_in, const int* in_sizes, int n_in,
                              void* d_out, int out_size, void* d_ws, size_t ws_size,
                              hipStream_t stream) {
    const float* x      = (const float*)d_in[0];
    const float* W_emb  = (const float*)d_in[1];
    const float* b_emb  = (const float*)d_in[2];
    const float* Wih_a  = (const float*)d_in[3];
    const float* Whh_a  = (const float*)d_in[4];
    const float* bih_a  = (const float*)d_in[5];
    const float* bhh_a  = (const float*)d_in[6];
    // d_in[7..10]: beta LSTM params — dead code in the reference, skipped.
    const float* W_aatt = (const float*)d_in[11];
    // d_in[12] (b_aatt): scalar shift of all scores — softmax-invariant, skipped.
    const float* W_batt = (const float*)d_in[13];
    const float* b_batt = (const float*)d_in[14];
    const float* W_mu   = (const float*)d_in[15];
    const float* b_mu   = (const float*)d_in[16];
    const float* W_sig  = (const float*)d_in[17];
    const float* b_sig  = (const float*)d_in[18];
    const float* ah0    = (const float*)d_in[19];
    const float* ac0    = (const float*)d_in[20];

    const size_t N_EMB = (size_t)BB_ * TT_ * DD_;   // 8,388,608
    const size_t N_GX  = (size_t)BB_ * TT_ * G4_;   // 33,554,432
    const size_t N_PS  = (size_t)BB_ * TT_ * 32;    // 524,288
    const size_t N_BH  = (size_t)BB_ * HH_;         // 32,768
    const size_t N_BAR = 8192;                      // 32 KB barrier region

    size_t need_floats = N_BAR + N_EMB + N_GX + N_PS + 2 * N_BH;
    if (ws_size < need_floats * sizeof(float)) return;

    float* ws     = (float*)d_ws;
    unsigned* cnt = (unsigned*)d_ws;                // counters + flags (32 KB)
    float* emb    = ws + N_BAR;
    float* gx     = emb + N_EMB;
    float* ps     = gx + N_GX;
    float* hT0    = ps + N_PS;
    float* hT1    = hT0 + N_BH;

    float* out_mu  = (float*)d_out;
    float* out_sig = out_mu + (size_t)BB_ * ODE_;

    // 0. zero the barrier counters + flags (graph-capturable)
    hipMemsetAsync(d_ws, 0, N_BAR * sizeof(float), stream);

    // 1. h0 -> blocked layout
    h0_transpose<<<dim3(128), dim3(256), 0, stream>>>(ah0, hT0);

    // 2. emb = x @ W_emb.T + b_emb        (M=16384, N=512, K=512)
    gemm_bt<0><<<dim3(DD_ / 128, (BB_ * TT_) / 128), dim3(256), 0, stream>>>(
        x, W_emb, b_emb, nullptr, emb, BB_ * TT_, DD_, DD_, 1.f);

    // 3. gx = emb @ Wih_a.T + bih_a + bhh_a   (M=16384, N=2048, K=512)
    gemm_bt<0><<<dim3(G4_ / 128, (BB_ * TT_) / 128), dim3(256), 0, stream>>>(
        emb, Wih_a, bih_a, bhh_a, gx, BB_ * TT_, G4_, DD_, 1.f);

    // 4. full recurrence + fused score partials in ONE persistent kernel
    lstm_persist<<<dim3(NBLK_), dim3(256), 0, stream>>>(
        gx, Whh_a, ac0, W_aatt, hT0, hT1, ps, cnt);
    // final h lands in hT0 (t=255 writes buffer 0)

    // 5. fused tail: score-sum + softmax + wsum + beta + var + mu + sigma
    fused_tail<<<dim3(BB_), dim3(256), 0, stream>>>(
        ps, emb, hT0, W_batt, b_batt, W_mu, b_mu, W_sig, b_sig,
        out_mu, out_sig);
}